// Round 1
// baseline (286.761 us; speedup 1.0000x reference)
//
#include <hip/hip_runtime.h>
#include <stdint.h>

#pragma clang fp contract(off)

typedef unsigned long long ull;

#define HIGHT 0.7f
#define LOWT  0.3f
#define NB1   32        // stage-1 top-k blocks per mode
#define SORT_N 2048     // stage-1 per-block sort size (>= ceil(50000/NB1))
#define MAXGT 512

// ---- total-order key: descending value, ties -> ascending index (jax top_k) ----
__device__ __forceinline__ unsigned key32_of_float(float f){
  unsigned u = __float_as_uint(f);
  return (u & 0x80000000u) ? ~u : (u | 0x80000000u);   // monotonic map for all floats
}
__device__ __forceinline__ ull pack_key(float f, unsigned idx){
  return ((ull)key32_of_float(f) << 32) | (ull)(0xFFFFFFFFu - idx);
}
__device__ __forceinline__ unsigned idx_of_key(ull k){
  return 0xFFFFFFFFu - (unsigned)(k & 0xFFFFFFFFull);
}

// ---- bit-exact IoU (matches numpy fp32 op-for-op; no contraction) ----
__device__ __forceinline__ float iou_pair(float ax0, float ay0, float ax1, float ay1, float aarea,
                                          float bx0, float by0, float bx1, float by1, float barea){
#pragma clang fp contract(off)
  float x0 = fmaxf(ax0, bx0);
  float y0 = fmaxf(ay0, by0);
  float x1 = fminf(ax1, bx1);
  float y1 = fminf(ay1, by1);
  float dx = fmaxf(x1 - x0, 0.0f);
  float dy = fmaxf(y1 - y0, 0.0f);
  float inter = dx * dy;
  float uni = (aarea + barea) - inter;   // (area1 + area2) - inter, as in reference
  return inter / uni;                    // correctly-rounded fp32 div (hipcc default)
}

// ---- K0: zero forced flags + neg counter (ws is poisoned 0xAA every call) ----
__global__ void init_kernel(unsigned int* __restrict__ forced_words, int nwords,
                            int* __restrict__ neg_count){
  int t = blockIdx.x * blockDim.x + threadIdx.x;
  if (t < nwords) forced_words[t] = 0u;
  if (t == 0) *neg_count = 0;
}

// ---- K1: per-proposal max IoU + argmax over GTs (first-max tie-break) ----
__global__ void row_kernel(const float4* __restrict__ boxes, const float4* __restrict__ gts,
                           int n1, int n2,
                           float* __restrict__ max_iou, int* __restrict__ input_idx){
#pragma clang fp contract(off)
  __shared__ float gx0[MAXGT], gy0[MAXGT], gx1[MAXGT], gy1[MAXGT], ga[MAXGT];
  for (int j = threadIdx.x; j < n2; j += blockDim.x){
    float4 g = gts[j];
    float hw = g.z * 0.5f, hh = g.w * 0.5f;   // w/2 exact
    gx0[j] = g.x - hw; gy0[j] = g.y - hh;
    gx1[j] = g.x + hw; gy1[j] = g.y + hh;
    ga[j]  = g.z * g.w;
  }
  __syncthreads();
  int i = blockIdx.x * blockDim.x + threadIdx.x;
  if (i >= n1) return;
  float4 p = boxes[i];
  float hw = p.z * 0.5f, hh = p.w * 0.5f;
  float px0 = p.x - hw, py0 = p.y - hh, px1 = p.x + hw, py1 = p.y + hh;
  float pa = p.z * p.w;
  float best = -1.0f; int bj = 0;
  for (int j = 0; j < n2; ++j){
    float v = iou_pair(px0, py0, px1, py1, pa, gx0[j], gy0[j], gx1[j], gy1[j], ga[j]);
    if (v > best){ best = v; bj = j; }        // strict > => first occurrence of max
  }
  max_iou[i] = best;
  input_idx[i] = bj;
}

// ---- K2: per-GT argmax over proposals (one block per GT, packed-key reduce) ----
__global__ void col_kernel(const float4* __restrict__ boxes, const float4* __restrict__ gts,
                           int n1, int n2, int* __restrict__ target_idx){
#pragma clang fp contract(off)
  int j = blockIdx.x;
  if (j >= n2) return;
  float4 g = gts[j];
  float ghw = g.z * 0.5f, ghh = g.w * 0.5f;
  float gx0 = g.x - ghw, gy0 = g.y - ghh, gx1 = g.x + ghw, gy1 = g.y + ghh;
  float ga = g.z * g.w;
  ull best = 0;
  for (int i = threadIdx.x; i < n1; i += blockDim.x){
    float4 p = boxes[i];
    float phw = p.z * 0.5f, phh = p.w * 0.5f;
    float v = iou_pair(p.x - phw, p.y - phh, p.x + phw, p.y + phh, p.z * p.w,
                       gx0, gy0, gx1, gy1, ga);
    ull key = pack_key(v, (unsigned)i);
    if (key > best) best = key;
  }
  __shared__ ull red[256];
  red[threadIdx.x] = best;
  __syncthreads();
  for (int s = 128; s > 0; s >>= 1){
    if (threadIdx.x < s && red[threadIdx.x + s] > red[threadIdx.x])
      red[threadIdx.x] = red[threadIdx.x + s];
    __syncthreads();
  }
  if (threadIdx.x == 0) target_idx[j] = (int)idx_of_key(red[0]);
}

// ---- K3: forced-positive scatter ----
__global__ void scatter_kernel(const int* __restrict__ target_idx, int n2,
                               unsigned char* __restrict__ forced){
  int j = blockIdx.x * blockDim.x + threadIdx.x;
  if (j < n2) forced[target_idx[j]] = 1;   // races write same value: benign
}

// ---- K4: count negatives (for the ~pos_mask fallback) ----
__global__ void count_kernel(const float* __restrict__ max_iou, const unsigned char* __restrict__ forced,
                             int n1, int* __restrict__ neg_count){
  int i = blockIdx.x * blockDim.x + threadIdx.x;
  if (i < n1 && max_iou[i] < LOWT && forced[i] == 0)
    atomicAdd(neg_count, 1);               // compiler wave-coalesces
}

// ---- K5: per-block exact top-128 via bitonic sort of SORT_N keys ----
__global__ void topk_stage1(const float* __restrict__ max_iou, const unsigned char* __restrict__ forced,
                            const float* __restrict__ pos_noise, const float* __restrict__ neg_noise,
                            const int* __restrict__ neg_count, int n1, int seg,
                            ull* __restrict__ cand){
  __shared__ ull keys[SORT_N];
  const int mode = blockIdx.y;             // 0 = pos, 1 = neg
  const int base = blockIdx.x * seg;
  const bool fallback = (*neg_count == 0);
  for (int t = threadIdx.x; t < SORT_N; t += blockDim.x){
    int i = base + t;
    ull key = 0;                           // pad: loses to every real key (incl. score -1.0)
    if (t < seg && i < n1){
      float m = max_iou[i];
      bool f = forced[i] != 0;
      bool pos = (m > HIGHT) || f;
      float score;
      if (mode == 0){
        score = pos ? pos_noise[i] : -1.0f;
      } else {
        bool neg = fallback ? (!pos) : ((m < LOWT) && !f);
        score = neg ? neg_noise[i] : -1.0f;
      }
      key = pack_key(score, (unsigned)i);
    }
    keys[t] = key;
  }
  __syncthreads();
  // full bitonic sort, descending
  for (unsigned kk = 2; kk <= SORT_N; kk <<= 1){
    for (unsigned j = kk >> 1; j > 0; j >>= 1){
      for (unsigned i = threadIdx.x; i < SORT_N; i += blockDim.x){
        unsigned ixj = i ^ j;
        if (ixj > i){
          ull a = keys[i], b = keys[ixj];
          bool up = ((i & kk) == 0);
          bool sw = up ? (a < b) : (a > b);
          if (sw){ keys[i] = b; keys[ixj] = a; }
        }
      }
      __syncthreads();
    }
  }
  for (int t = threadIdx.x; t < 128; t += blockDim.x)
    cand[(mode * NB1 + blockIdx.x) * 128 + t] = keys[t];
}

// ---- K6: merge tree of NB1 sorted 128-lists -> global top-128, write outputs ----
__global__ void topk_stage2(const ull* __restrict__ cand, const int* __restrict__ input_idx,
                            int* __restrict__ out){
  __shared__ ull keys[NB1 * 128];
  const int mode = blockIdx.y;
  for (int t = threadIdx.x; t < NB1 * 128; t += blockDim.x)
    keys[t] = cand[mode * NB1 * 128 + t];
  __syncthreads();
  int nl = NB1;
  while (nl > 1){
    int pairs = nl >> 1;
    int tot = pairs * 128;
    // substep 1: A[i] vs B[127-i] (bitonic merge of A ++ reverse(B))
    for (int t = threadIdx.x; t < tot; t += blockDim.x){
      int m = t >> 7, i = t & 127, base = m << 8;
      ull a = keys[base + i], b = keys[base + 255 - i];
      if (b > a){ keys[base + i] = b; keys[base + 255 - i] = a; }
    }
    __syncthreads();
    // finish sorting the (bitonic) top half of each 256-segment, descending
    for (int j = 64; j > 0; j >>= 1){
      for (int t = threadIdx.x; t < tot; t += blockDim.x){
        int m = t >> 7, i = t & 127;
        if ((i & j) == 0){
          int base = m << 8;
          ull a = keys[base + i], b = keys[base + (i | j)];
          if (b > a){ keys[base + i] = b; keys[base + (i | j)] = a; }
        }
      }
      __syncthreads();
    }
    // compact: winner list m (at offset 256m) -> offset 128m
    ull tmp[8];
    int q = 0;
    for (int t = threadIdx.x; t < tot; t += blockDim.x, ++q){
      int m = t >> 7, i = t & 127;
      tmp[q] = keys[(m << 8) + i];
    }
    __syncthreads();
    q = 0;
    for (int t = threadIdx.x; t < tot; t += blockDim.x, ++q)
      keys[t] = tmp[q];
    __syncthreads();
    nl = pairs;
  }
  for (int t = threadIdx.x; t < 128; t += blockDim.x){
    unsigned idx = idx_of_key(keys[t]);
    if (mode == 0){
      out[t] = (int)idx;                 // pos_input_idx
      out[128 + t] = input_idx[idx];     // pos_target_idx
    } else {
      out[256 + t] = (int)idx;           // neg_input_idx
    }
  }
}

extern "C" void kernel_launch(void* const* d_in, const int* in_sizes, int n_in,
                              void* d_out, int out_size, void* d_ws, size_t ws_size,
                              hipStream_t stream){
  const float4* boxes = (const float4*)d_in[0];   // (1, 50000, 4) f32
  const float4* gts   = (const float4*)d_in[1];   // (1, 512, 4) f32
  const float* pos_noise = (const float*)d_in[2]; // (50000,) f32
  const float* neg_noise = (const float*)d_in[3]; // (50000,) f32
  const int n1 = in_sizes[0] / 4;
  const int n2 = in_sizes[1] / 4;
  int* out = (int*)d_out;                          // 128+128+128 int32

  // workspace carve-up (256B-aligned regions)
  char* ws = (char*)d_ws;
  size_t off = 0;
  auto carve = [&](size_t bytes) -> char* {
    char* p = ws + off;
    off = (off + bytes + 255) & ~(size_t)255;
    return p;
  };
  float* max_iou   = (float*)carve((size_t)n1 * 4);
  int*   input_idx = (int*)  carve((size_t)n1 * 4);
  int*   target_idx= (int*)  carve((size_t)n2 * 4);
  unsigned char* forced = (unsigned char*)carve(((size_t)n1 + 3) & ~(size_t)3);
  int*   neg_count = (int*)  carve(4);
  ull*   cand      = (ull*)  carve((size_t)2 * NB1 * 128 * 8);

  const int fw = (n1 + 3) / 4;
  init_kernel<<<(fw + 255) / 256, 256, 0, stream>>>((unsigned int*)forced, fw, neg_count);
  row_kernel<<<(n1 + 255) / 256, 256, 0, stream>>>(boxes, gts, n1, n2, max_iou, input_idx);
  col_kernel<<<n2, 256, 0, stream>>>(boxes, gts, n1, n2, target_idx);
  scatter_kernel<<<(n2 + 255) / 256, 256, 0, stream>>>(target_idx, n2, forced);
  count_kernel<<<(n1 + 255) / 256, 256, 0, stream>>>(max_iou, forced, n1, neg_count);
  const int seg = (n1 + NB1 - 1) / NB1;   // 1563 <= SORT_N
  dim3 g1(NB1, 2);
  topk_stage1<<<g1, 256, 0, stream>>>(max_iou, forced, pos_noise, neg_noise, neg_count, n1, seg, cand);
  dim3 g2(1, 2);
  topk_stage2<<<g2, 256, 0, stream>>>(cand, input_idx, out);
}